// Round 1
// baseline (44.155 us; speedup 1.0000x reference)
//
#include <hip/hip_runtime.h>

namespace {

constexpr int OUT_F = 11008;
constexpr int IN_F  = 4096;

typedef int   int4v   __attribute__((ext_vector_type(4)));
typedef float float4v __attribute__((ext_vector_type(4)));

constexpr int ROWS_PER_WAVE   = 4;   // each wave computes 4 output rows
constexpr int WAVES_PER_BLOCK = 4;
constexpr int ROWS_PER_BLOCK  = ROWS_PER_WAVE * WAVES_PER_BLOCK;  // 16
constexpr int K_STEPS         = IN_F / (64 * 4);                  // 16

__global__ __launch_bounds__(256, 2) void qlinear_kernel(
    const float* __restrict__ x,       // [4, IN_F]
    const int*   __restrict__ qw,      // [OUT_F, IN_F] int32 values in [-127,127]
    const float* __restrict__ scales,  // [OUT_F]
    const float* __restrict__ bias,    // [OUT_F]
    float*       __restrict__ out)     // [4, OUT_F]
{
    const int lane = threadIdx.x & 63;
    const int wid  = threadIdx.x >> 6;
    const int row0 = blockIdx.x * ROWS_PER_BLOCK + wid * ROWS_PER_WAVE;

    float acc[ROWS_PER_WAVE][4];
#pragma unroll
    for (int r = 0; r < ROWS_PER_WAVE; ++r)
#pragma unroll
        for (int b = 0; b < 4; ++b)
            acc[r][b] = 0.0f;

#pragma unroll 4
    for (int k = 0; k < K_STEPS; ++k) {
        const int off = k * 256 + lane * 4;

        int4v w[ROWS_PER_WAVE];
#pragma unroll
        for (int r = 0; r < ROWS_PER_WAVE; ++r)
            w[r] = *(const int4v*)(qw + (size_t)(row0 + r) * IN_F + off);

        float4v xv[4];
#pragma unroll
        for (int b = 0; b < 4; ++b)
            xv[b] = *(const float4v*)(x + b * IN_F + off);

#pragma unroll
        for (int r = 0; r < ROWS_PER_WAVE; ++r) {
            float4v wf;
            wf.x = (float)w[r].x;
            wf.y = (float)w[r].y;
            wf.z = (float)w[r].z;
            wf.w = (float)w[r].w;
#pragma unroll
            for (int b = 0; b < 4; ++b) {
                acc[r][b] += wf.x * xv[b].x;
                acc[r][b] += wf.y * xv[b].y;
                acc[r][b] += wf.z * xv[b].z;
                acc[r][b] += wf.w * xv[b].w;
            }
        }
    }

    // Butterfly reduction across the 64 lanes (sum lands in every lane).
#pragma unroll
    for (int r = 0; r < ROWS_PER_WAVE; ++r)
#pragma unroll
        for (int b = 0; b < 4; ++b) {
            float v = acc[r][b];
#pragma unroll
            for (int m = 32; m >= 1; m >>= 1)
                v += __shfl_xor(v, m, 64);
            acc[r][b] = v;
        }

    if (lane == 0) {
#pragma unroll
        for (int r = 0; r < ROWS_PER_WAVE; ++r) {
            const int row = row0 + r;
            const float s  = scales[row];
            const float bz = bias[row];
#pragma unroll
            for (int b = 0; b < 4; ++b)
                out[(size_t)b * OUT_F + row] = acc[r][b] * s + bz;
        }
    }
}

}  // namespace

extern "C" void kernel_launch(void* const* d_in, const int* in_sizes, int n_in,
                              void* d_out, int out_size, void* d_ws, size_t ws_size,
                              hipStream_t stream) {
    const float* x      = (const float*)d_in[0];
    const int*   qw     = (const int*)d_in[1];
    const float* scales = (const float*)d_in[2];
    const float* bias   = (const float*)d_in[3];
    float*       out    = (float*)d_out;

    const int grid = OUT_F / ROWS_PER_BLOCK;  // 688
    qlinear_kernel<<<grid, 256, 0, stream>>>(x, qw, scales, bias, out);
}

// Round 2
// 34.136 us; speedup vs baseline: 1.2935x; 1.2935x over previous
//
#include <hip/hip_runtime.h>

namespace {

constexpr int OUT_F = 11008;
constexpr int IN_F  = 4096;

typedef int   int4v   __attribute__((ext_vector_type(4)));
typedef float float4v __attribute__((ext_vector_type(4)));

constexpr int ROWS_PER_WAVE   = 2;
constexpr int WAVES_PER_BLOCK = 4;
constexpr int ROWS_PER_BLOCK  = ROWS_PER_WAVE * WAVES_PER_BLOCK;  // 8
constexpr int K_STEPS         = IN_F / (64 * 4);                  // 16 (4 floats/lane/step)
constexpr int CHUNK           = 4;                                // pipeline depth in steps
constexpr int NCHUNK          = K_STEPS / CHUNK;                  // 4

__global__ __launch_bounds__(256, 4) void qlinear_kernel(
    const float* __restrict__ x,       // [4, IN_F]
    const int*   __restrict__ qw,      // [OUT_F, IN_F] int8 values in int32
    const float* __restrict__ scales,  // [OUT_F]
    const float* __restrict__ bias,    // [OUT_F]
    float*       __restrict__ out)     // [4, OUT_F]
{
    // Stage all of x (4 x 4096 fp32 = 64 KB) into LDS once per block.
    __shared__ float4v xs[4 * (IN_F / 4)];

    const int tid = threadIdx.x;
    const float4v* xg = (const float4v*)x;
#pragma unroll
    for (int j = 0; j < (4 * IN_F / 4) / 256; ++j)  // 16 iters x 256 threads
        xs[j * 256 + tid] = xg[j * 256 + tid];
    __syncthreads();

    const int lane = tid & 63;
    const int wid  = tid >> 6;
    const int row0 = blockIdx.x * ROWS_PER_BLOCK + wid * ROWS_PER_WAVE;

    const int4v* wp0 = (const int4v*)(qw + (size_t)row0 * IN_F);
    const int4v* wp1 = (const int4v*)(qw + (size_t)(row0 + 1) * IN_F);

    float acc[ROWS_PER_WAVE][4];
#pragma unroll
    for (int r = 0; r < ROWS_PER_WAVE; ++r)
#pragma unroll
        for (int b = 0; b < 4; ++b)
            acc[r][b] = 0.0f;

    // Register double-buffer: while computing chunk c, chunk c+1's 8 loads
    // (2 rows x 4 steps x 1 KB/wave) are in flight.
    int4v wa[ROWS_PER_WAVE][CHUNK], wb[ROWS_PER_WAVE][CHUNK];

#pragma unroll
    for (int s = 0; s < CHUNK; ++s) {
        wa[0][s] = wp0[s * 64 + lane];
        wa[1][s] = wp1[s * 64 + lane];
    }

#pragma unroll
    for (int c = 0; c < NCHUNK; ++c) {
        if (c + 1 < NCHUNK) {
#pragma unroll
            for (int s = 0; s < CHUNK; ++s) {
                wb[0][s] = wp0[((c + 1) * CHUNK + s) * 64 + lane];
                wb[1][s] = wp1[((c + 1) * CHUNK + s) * 64 + lane];
            }
        }

#pragma unroll
        for (int s = 0; s < CHUNK; ++s) {
            const int k = c * CHUNK + s;
            float4v xv[4];
#pragma unroll
            for (int b = 0; b < 4; ++b)
                xv[b] = xs[b * (IN_F / 4) + k * 64 + lane];

#pragma unroll
            for (int r = 0; r < ROWS_PER_WAVE; ++r) {
                float4v wf;
                wf.x = (float)wa[r][s].x;
                wf.y = (float)wa[r][s].y;
                wf.z = (float)wa[r][s].z;
                wf.w = (float)wa[r][s].w;
#pragma unroll
                for (int b = 0; b < 4; ++b) {
                    acc[r][b] += wf.x * xv[b].x;
                    acc[r][b] += wf.y * xv[b].y;
                    acc[r][b] += wf.z * xv[b].z;
                    acc[r][b] += wf.w * xv[b].w;
                }
            }
        }

        if (c + 1 < NCHUNK) {
#pragma unroll
            for (int s = 0; s < CHUNK; ++s) {
                wa[0][s] = wb[0][s];
                wa[1][s] = wb[1][s];
            }
        }
    }

    // Butterfly reduction across the 64 lanes.
#pragma unroll
    for (int r = 0; r < ROWS_PER_WAVE; ++r)
#pragma unroll
        for (int b = 0; b < 4; ++b) {
            float v = acc[r][b];
#pragma unroll
            for (int m = 32; m >= 1; m >>= 1)
                v += __shfl_xor(v, m, 64);
            acc[r][b] = v;
        }

    if (lane == 0) {
#pragma unroll
        for (int r = 0; r < ROWS_PER_WAVE; ++r) {
            const int row = row0 + r;
            const float s  = scales[row];
            const float bz = bias[row];
#pragma unroll
            for (int b = 0; b < 4; ++b)
                out[(size_t)b * OUT_F + row] = acc[r][b] * s + bz;
        }
    }
}

}  // namespace

extern "C" void kernel_launch(void* const* d_in, const int* in_sizes, int n_in,
                              void* d_out, int out_size, void* d_ws, size_t ws_size,
                              hipStream_t stream) {
    const float* x      = (const float*)d_in[0];
    const int*   qw     = (const int*)d_in[1];
    const float* scales = (const float*)d_in[2];
    const float* bias   = (const float*)d_in[3];
    float*       out    = (float*)d_out;

    const int grid = OUT_F / ROWS_PER_BLOCK;  // 1376
    qlinear_kernel<<<grid, 256, 0, stream>>>(x, qw, scales, bias, out);
}